// Round 9
// baseline (217.151 us; speedup 1.0000x reference)
//
#include <hip/hip_runtime.h>
#include <math.h>

#define EPSF 1e-8f

typedef _Float16 f16x8 __attribute__((ext_vector_type(8)));
typedef float    f32x4 __attribute__((ext_vector_type(4)));

constexpr int Bb = 8, Nn = 32768, Kk = 64, Dd = 64;

// GEMM-ified: C[k][n] = sum_d slots[k][d] * features[n][d] via
// v_mfma_f32_16x16x32_f16 with fp32 operands split hi/lo into f16
// (3 products: hi*hi + hi*lo + lo*hi ~ fp32-accurate).
//
// Round-9 revision. Evidence ledger:
//   r0 60.8 | r2 43.6 | r3 ~42 | r4 47.4 | r5 41.4 | r6 66.4 | r7 66.8 | r8 43.5
//   Facts: warm runs (FETCH~0) take EXACTLY as long as cold -> no
//   bandwidth theory survives. LDS store staging +25us (r6/r7). XCD
//   remap null (r8). VALUBusy*dur ~ 14us, MfmaUtil*dur ~ 2.3us invariant.
//   OccupancyPercent 17-21% = ~6 waves/CU time-avg vs 12 nominal: the
//   3+1 two-generation schedule leaves a long depleted tail at ~1
//   wave/SIMD. Duration tracks waves/CU x per-wave chain (r2/r4/r5).
// Changes (two orthogonal, safe):
//  (a) NON-TEMPORAL stores: bypass dirty-L2/L3 eviction path, stream in
//      issue order, stop polluting L3 (the only never-touched pipe).
//  (b) tail-free grid: 512 blocks = 2/CU exactly, ONE generation; each
//      wave runs 2 sequential 4-tile groups; group-2 loads issue during
//      group-1's normalize/store phase (buf regs dead there).
__global__ __launch_bounds__(256, 3) void attn_kernel(
    const float* __restrict__ features,
    const float* __restrict__ slots,
    const float* __restrict__ horizons,
    float* __restrict__ out)
{
    __shared__ float4 s_kp[Kk];      // (st, ss2_spatial, 1/(h+eps), pad)
    __shared__ f16x8 s_ahi[8][64];   // [t*2+c][lane] 8KB
    __shared__ f16x8 s_alo[8][64];   // 8KB

    const int tid  = threadIdx.x;
    const int bid  = blockIdx.x;
    const int b    = bid >> 6;        // 64 blocks per batch
    const int blk  = bid & 63;
    const int lane = tid & 63;
    const int wid  = tid >> 6;
    const int m    = lane & 15;       // MFMA row/col lane index
    const int quad = lane >> 4;

    // ---- per-block slot constants, packed; unroll 4 caps reg spike ----
    if (tid < Kk) {
        const float4* sr = (const float4*)(slots + (size_t)(b * Kk + tid) * Dd);
        float st = 0.f, ss = 0.f;
        #pragma unroll 4
        for (int i = 0; i < 16; ++i) {
            float4 u = sr[i];
            if (i == 0) st = u.x;
            ss += u.x * u.x + u.y * u.y + u.z * u.z + u.w * u.w;
        }
        ss -= st * st;               // exclude time dim d0
        s_kp[tid] = make_float4(st, ss, 1.0f / (horizons[b * Kk + tid] + EPSF), 0.f);
    }

    // ---- cooperative A staging: thread (t=wid, lane) splits 2 fragments ----
    {
        const int t = wid;
        #pragma unroll
        for (int c = 0; c < 2; ++c) {
            const float* sp = slots + (size_t)(b * Kk + 16 * t + m) * Dd
                            + 32 * c + quad * 8;
            float4 u0 = *(const float4*)sp;
            float4 u1 = *(const float4*)(sp + 4);
            float fv[8] = {u0.x, u0.y, u0.z, u0.w, u1.x, u1.y, u1.z, u1.w};
            if (c == 0 && quad == 0) fv[0] = 0.0f;     // time dim out of dot
            f16x8 h8, l8;
            #pragma unroll
            for (int j = 0; j < 8; ++j) {
                float x = fv[j];
                _Float16 h = (_Float16)x;              // RN split
                _Float16 l = (_Float16)(x - (float)h);
                h8[j] = h;
                l8[j] = l;
            }
            s_ahi[t * 2 + c][lane] = h8;
            s_alo[t * 2 + c][lane] = l8;
        }
    }
    __syncthreads();

    // wave covers 128 n: 2 groups x 4 fused tiles x 16
    const int nw = (blk * 32 + wid * 8) * 16;

    // ---- prologue: group-0 loads (16 dwordx4 in flight) ----
    float4 buf[4][4];
    #pragma unroll
    for (int it = 0; it < 4; ++it) {
        const float* fp = features + (((size_t)b << 15) + nw + it * 16 + m) * Dd
                        + quad * 8;
        buf[it][0] = *(const float4*)(fp);
        buf[it][1] = *(const float4*)(fp + 4);
        buf[it][2] = *(const float4*)(fp + 32);
        buf[it][3] = *(const float4*)(fp + 36);
    }

    #pragma unroll
    for (int g = 0; g < 2; ++g) {
        const int n0 = nw + g * 64;

        // ---- split group's 4 tiles into f16 hi/lo fragments + fs2 ----
        f16x8 bh[4][2], bl[4][2];
        float ft[4], fs2[4];
        #pragma unroll
        for (int it = 0; it < 4; ++it) {
            const float f00 = buf[it][0].x;    // quad==0 lanes hold f[n][0]
            float s = 0.f;
            #pragma unroll
            for (int c = 0; c < 2; ++c) {
                float4 u0 = buf[it][2 * c];
                float4 u1 = buf[it][2 * c + 1];
                float fv[8] = {u0.x, u0.y, u0.z, u0.w, u1.x, u1.y, u1.z, u1.w};
                #pragma unroll
                for (int j = 0; j < 8; ++j) {
                    float x = fv[j];
                    s = fmaf(x, x, s);
                    _Float16 h = (_Float16)x;
                    _Float16 l = (_Float16)(x - (float)h);
                    bh[it][c][j] = h;
                    bl[it][c][j] = l;
                }
            }
            float f = __shfl(f00, m);          // lane m (<16, quad 0)
            s += __shfl_xor(s, 16);
            s += __shfl_xor(s, 32);            // full |f|^2 over 64 d
            ft[it]  = f;
            fs2[it] = fmaf(-f, f, s);          // spatial only
        }

        // ---- 96 MFMAs: per A-read, 4 independent 6-chains ----
        f32x4 acc[4][4];                       // [it][t]
        #pragma unroll
        for (int t = 0; t < 4; ++t) {
            f16x8 ah0 = s_ahi[t * 2 + 0][lane];
            f16x8 ah1 = s_ahi[t * 2 + 1][lane];
            f16x8 al0 = s_alo[t * 2 + 0][lane];
            f16x8 al1 = s_alo[t * 2 + 1][lane];
            #pragma unroll
            for (int it = 0; it < 4; ++it) {
                f32x4 a = {0.f, 0.f, 0.f, 0.f};
                a = __builtin_amdgcn_mfma_f32_16x16x32_f16(ah0, bh[it][0], a, 0, 0, 0);
                a = __builtin_amdgcn_mfma_f32_16x16x32_f16(ah0, bl[it][0], a, 0, 0, 0);
                a = __builtin_amdgcn_mfma_f32_16x16x32_f16(al0, bh[it][0], a, 0, 0, 0);
                a = __builtin_amdgcn_mfma_f32_16x16x32_f16(ah1, bh[it][1], a, 0, 0, 0);
                a = __builtin_amdgcn_mfma_f32_16x16x32_f16(ah1, bl[it][1], a, 0, 0, 0);
                a = __builtin_amdgcn_mfma_f32_16x16x32_f16(al1, bh[it][1], a, 0, 0, 0);
                acc[it][t] = a;
            }
        }

        // ---- epilogue: one packed kparam read serves all 4 tiles ----
        float sum[4] = {0.f, 0.f, 0.f, 0.f};
        #pragma unroll
        for (int t = 0; t < 4; ++t) {
            #pragma unroll
            for (int r = 0; r < 4; ++r) {
                const int k = 16 * t + quad * 4 + r;   // C row
                float4 kp = s_kp[k];                   // st, ss2, rh
                #pragma unroll
                for (int it = 0; it < 4; ++it) {       // 4 independent chains
                    float cross = acc[it][t][r];
                    float dt  = ft[it] - kp.x;
                    float dx2 = fmaf(-2.f, cross, fs2[it] + kp.y);
                    dx2 = fmaxf(dx2, 0.f);
                    float interval = fmaf(dt, dt, -dx2);
                    float adist = __builtin_amdgcn_sqrtf(fabsf(interval) + EPSF);
                    float cone  = (fabsf(dt) - __builtin_amdgcn_sqrtf(dx2 + EPSF)) * kp.z;
                    float e  = __expf(2.0f * cone);    // tanh via exp, NaN-free
                    float th = 1.0f - 2.0f * __builtin_amdgcn_rcpf(e + 1.0f);
                    float logit = fmaf(0.5f, th, -adist);  // <= +0.5: exp safe
                    float pe = __expf(logit);
                    acc[it][t][r] = pe;                // overlay: acc reused as p
                    sum[it] += pe;
                }
            }
        }

        // ---- group-1 loads issue here: overlap with inv + stores ----
        if (g == 0) {
            #pragma unroll
            for (int it = 0; it < 4; ++it) {
                const float* fp = features + (((size_t)b << 15) + nw + 64 + it * 16 + m) * Dd
                                + quad * 8;
                buf[it][0] = *(const float4*)(fp);
                buf[it][1] = *(const float4*)(fp + 4);
                buf[it][2] = *(const float4*)(fp + 32);
                buf[it][3] = *(const float4*)(fp + 36);
            }
        }

        float inv[4];
        #pragma unroll
        for (int it = 0; it < 4; ++it) {
            float s = sum[it];
            s += __shfl_xor(s, 16);
            s += __shfl_xor(s, 32);                    // total over 64 k
            inv[it] = __builtin_amdgcn_rcpf(s);
        }

        // ---- non-temporal stores: stream in issue order, no L2/L3 dirty
        //      eviction, no L3 pollution of features ----
        float* ob = out + (((size_t)(b * Kk)) << 15) + n0 + m;
        #pragma unroll
        for (int t = 0; t < 4; ++t) {
            #pragma unroll
            for (int r = 0; r < 4; ++r) {
                const int k = 16 * t + quad * 4 + r;
                #pragma unroll
                for (int it = 0; it < 4; ++it) {
                    __builtin_nontemporal_store(acc[it][t][r] * inv[it],
                                                &ob[((size_t)k << 15) + it * 16]);
                }
            }
        }
    }
}

extern "C" void kernel_launch(void* const* d_in, const int* in_sizes, int n_in,
                              void* d_out, int out_size, void* d_ws, size_t ws_size,
                              hipStream_t stream) {
    const float* features = (const float*)d_in[0];
    const float* slots    = (const float*)d_in[1];
    const float* horizons = (const float*)d_in[2];
    float* out = (float*)d_out;

    // 512 blocks x 256 thr = 2048 waves: 2 blocks/CU exactly, ONE
    // generation (no depleted tail). Each wave: 2 groups x 4 tiles x 16 n.
    hipLaunchKernelGGL(attn_kernel, dim3(512), dim3(256), 0, stream,
                       features, slots, horizons, out);
}

// Round 11
// 134.106 us; speedup vs baseline: 1.6192x; 1.6192x over previous
//
#include <hip/hip_runtime.h>
#include <math.h>

#define EPSF 1e-8f
#define LOG2E 1.4426950408889634f

typedef _Float16 f16x8 __attribute__((ext_vector_type(8)));
typedef float    f32x4 __attribute__((ext_vector_type(4)));

constexpr int Bb = 8, Nn = 32768, Kk = 64, Dd = 64;

// GEMM-ified: C[k][n] = sum_d slots[k][d] * features[n][d] via
// v_mfma_f32_16x16x32_f16 with fp32 operands split hi/lo into f16
// (3 products: hi*hi + hi*lo + lo*hi ~ fp32-accurate).
//
// Round-11 = round-10 resubmitted verbatim (r10 bench died on an infra
// error: "MI355X container failed twice"; no data). Evidence ledger:
//   r0 60.8 | r2 43.6 | r3 ~42 | r4 47.4 | r5 41.4 | r6 66.4 | r7 66.8
//   | r8 43.5 | r9 162-180 (nt stores: L2 bypass -> 288MB partial-line
//   writes + RMW fetches. Inversion: normal path's exact-64MB WRITE means
//   L2 already merges perfectly. ALL memory-side theories now dead.)
//   Fits: marginal ~5.9K cy/tile serial per wave; VALUBusy*dur ~ 14us
//   invariant; port ~33% busy; occupancy pinned ~3 waves/SIMD across ALL
//   launch_bounds (even VGPR=44 @ (256,5)) -> suspect unified-file AGPR
//   side (acc 64 + frags ~48 + misc ~ 170/wave -> 512/170 = 3).
// Changes vs r5 (the best kernel):
//  (a) launch_bounds(256,4): force total unified regs <= 128 -> 4
//      waves/SIMD. Spill tripwire: FETCH/WRITE must stay 33/65.5 MB.
//  (b) epilogue diet: kp.z = 2*log2e/(h+eps) precomputed; p computed as
//      exp2(fma(-log2e, r, c0)), c0 = fma(-log2e, adist, 0.5*log2e)
//      [identical real function: p = exp(0.5 - r - adist), th = 1-2r];
//      exp2 via v_exp_f32 directly (no log2e mul inside __expf).
//      ~3-4 fewer VALU per logit, 2 fewer muls per exp pair.
__global__ __launch_bounds__(256, 4) void attn_kernel(
    const float* __restrict__ features,
    const float* __restrict__ slots,
    const float* __restrict__ horizons,
    float* __restrict__ out)
{
    __shared__ float4 s_kp[Kk];      // (st, ss2_spatial, 2*log2e/(h+eps), 0)
    __shared__ f16x8 s_ahi[8][64];   // [t*2+c][lane] 8KB
    __shared__ f16x8 s_alo[8][64];   // 8KB

    const int tid  = threadIdx.x;
    const int bid  = blockIdx.x;
    const int b    = bid >> 7;        // 128 blocks per batch
    const int blk  = bid & 127;
    const int lane = tid & 63;
    const int wid  = tid >> 6;
    const int m    = lane & 15;       // MFMA row/col lane index
    const int quad = lane >> 4;

    // ---- per-block slot constants, packed; unroll 4 caps reg spike ----
    if (tid < Kk) {
        const float4* sr = (const float4*)(slots + (size_t)(b * Kk + tid) * Dd);
        float st = 0.f, ss = 0.f;
        #pragma unroll 4
        for (int i = 0; i < 16; ++i) {
            float4 u = sr[i];
            if (i == 0) st = u.x;
            ss += u.x * u.x + u.y * u.y + u.z * u.z + u.w * u.w;
        }
        ss -= st * st;               // exclude time dim d0
        s_kp[tid] = make_float4(st, ss,
                                (2.0f * LOG2E) / (horizons[b * Kk + tid] + EPSF),
                                0.f);
    }

    // ---- cooperative A staging: thread (t=wid, lane) splits 2 fragments ----
    {
        const int t = wid;
        #pragma unroll
        for (int c = 0; c < 2; ++c) {
            const float* sp = slots + (size_t)(b * Kk + 16 * t + m) * Dd
                            + 32 * c + quad * 8;
            float4 u0 = *(const float4*)sp;
            float4 u1 = *(const float4*)(sp + 4);
            float fv[8] = {u0.x, u0.y, u0.z, u0.w, u1.x, u1.y, u1.z, u1.w};
            if (c == 0 && quad == 0) fv[0] = 0.0f;     // time dim out of dot
            f16x8 h8, l8;
            #pragma unroll
            for (int j = 0; j < 8; ++j) {
                float x = fv[j];
                _Float16 h = (_Float16)x;              // RN split
                _Float16 l = (_Float16)(x - (float)h);
                h8[j] = h;
                l8[j] = l;
            }
            s_ahi[t * 2 + c][lane] = h8;
            s_alo[t * 2 + c][lane] = l8;
        }
    }
    __syncthreads();

    const int n0 = (blk * 16 + wid * 4) * 16;   // 4 consecutive 16-n tiles, fused

    // ---- all 4 tiles' loads issued up front: 16 dwordx4 in flight ----
    float4 buf[4][4];
    #pragma unroll
    for (int it = 0; it < 4; ++it) {
        const float* fp = features + (((size_t)b << 15) + n0 + it * 16 + m) * Dd
                        + quad * 8;
        buf[it][0] = *(const float4*)(fp);
        buf[it][1] = *(const float4*)(fp + 4);
        buf[it][2] = *(const float4*)(fp + 32);
        buf[it][3] = *(const float4*)(fp + 36);
    }

    // ---- split all 4 tiles into f16 hi/lo fragments + fs2 ----
    f16x8 bh[4][2], bl[4][2];
    float ft[4], fs2[4];
    #pragma unroll
    for (int it = 0; it < 4; ++it) {
        const float f00 = buf[it][0].x;        // quad==0 lanes hold f[n][0]
        float s = 0.f;
        #pragma unroll
        for (int c = 0; c < 2; ++c) {
            float4 u0 = buf[it][2 * c];
            float4 u1 = buf[it][2 * c + 1];
            float fv[8] = {u0.x, u0.y, u0.z, u0.w, u1.x, u1.y, u1.z, u1.w};
            #pragma unroll
            for (int j = 0; j < 8; ++j) {
                float x = fv[j];
                s = fmaf(x, x, s);
                _Float16 h = (_Float16)x;
                _Float16 l = (_Float16)(x - (float)h);
                bh[it][c][j] = h;
                bl[it][c][j] = l;
            }
        }
        float f = __shfl(f00, m);              // lane m (<16, quad 0)
        s += __shfl_xor(s, 16);
        s += __shfl_xor(s, 32);                // full |f|^2 over 64 d
        ft[it]  = f;
        fs2[it] = fmaf(-f, f, s);              // spatial only
    }

    // ---- 96 MFMAs: per A-read, 4 independent 6-chains (16 chains total) ----
    f32x4 acc[4][4];                           // [it][t]
    #pragma unroll
    for (int t = 0; t < 4; ++t) {
        f16x8 ah0 = s_ahi[t * 2 + 0][lane];
        f16x8 ah1 = s_ahi[t * 2 + 1][lane];
        f16x8 al0 = s_alo[t * 2 + 0][lane];
        f16x8 al1 = s_alo[t * 2 + 1][lane];
        #pragma unroll
        for (int it = 0; it < 4; ++it) {
            f32x4 a = {0.f, 0.f, 0.f, 0.f};
            a = __builtin_amdgcn_mfma_f32_16x16x32_f16(ah0, bh[it][0], a, 0, 0, 0);
            a = __builtin_amdgcn_mfma_f32_16x16x32_f16(ah0, bl[it][0], a, 0, 0, 0);
            a = __builtin_amdgcn_mfma_f32_16x16x32_f16(al0, bh[it][0], a, 0, 0, 0);
            a = __builtin_amdgcn_mfma_f32_16x16x32_f16(ah1, bh[it][1], a, 0, 0, 0);
            a = __builtin_amdgcn_mfma_f32_16x16x32_f16(ah1, bl[it][1], a, 0, 0, 0);
            a = __builtin_amdgcn_mfma_f32_16x16x32_f16(al1, bh[it][1], a, 0, 0, 0);
            acc[it][t] = a;
        }
    }

    // ---- epilogue (diet): p = exp2(-log2e*r + c0), c0 = -log2e*adist + C05
    //      where r = 1/(e2c+1), e2c = exp2((|dt|-s)*kp.z), kp.z = 2*log2e*rh.
    //      Identical real function to exp(0.5*tanh(cone) - adist). ----
    const float C05 = 0.5f * LOG2E;
    float sum[4] = {0.f, 0.f, 0.f, 0.f};
    #pragma unroll
    for (int t = 0; t < 4; ++t) {
        #pragma unroll
        for (int r = 0; r < 4; ++r) {
            const int k = 16 * t + quad * 4 + r;   // C row
            float4 kp = s_kp[k];                   // st, ss2, 2*log2e*rh
            #pragma unroll
            for (int it = 0; it < 4; ++it) {       // 4 independent chains
                float cross = acc[it][t][r];
                float dt  = ft[it] - kp.x;
                float dx2 = fmaf(-2.f, cross, fs2[it] + kp.y);
                dx2 = fmaxf(dx2, 0.f);
                float iv  = fmaf(dt, dt, -dx2);
                float adist = __builtin_amdgcn_sqrtf(fabsf(iv) + EPSF);
                float sq    = __builtin_amdgcn_sqrtf(dx2 + EPSF);
                float e2c = __builtin_amdgcn_exp2f((fabsf(dt) - sq) * kp.z);
                float rr  = __builtin_amdgcn_rcpf(e2c + 1.0f);   // e2c=inf->0, =0->1
                float c0  = fmaf(-LOG2E, adist, C05);
                float pe  = __builtin_amdgcn_exp2f(fmaf(-LOG2E, rr, c0));
                acc[it][t][r] = pe;                // overlay: acc reused as p
                sum[it] += pe;
            }
        }
    }
    float inv[4];
    #pragma unroll
    for (int it = 0; it < 4; ++it) {
        float s = sum[it];
        s += __shfl_xor(s, 16);
        s += __shfl_xor(s, 32);                    // total over 64 k
        inv[it] = __builtin_amdgcn_rcpf(s);
    }

    // ---- stores: direct (r5 style); it-segments merge to 256B in L2 ----
    float* ob = out + (((size_t)(b * Kk)) << 15) + n0 + m;
    #pragma unroll
    for (int t = 0; t < 4; ++t) {
        #pragma unroll
        for (int r = 0; r < 4; ++r) {
            const int k = 16 * t + quad * 4 + r;
            #pragma unroll
            for (int it = 0; it < 4; ++it) {
                ob[((size_t)k << 15) + it * 16] = acc[it][t][r] * inv[it];
            }
        }
    }
}

extern "C" void kernel_launch(void* const* d_in, const int* in_sizes, int n_in,
                              void* d_out, int out_size, void* d_ws, size_t ws_size,
                              hipStream_t stream) {
    const float* features = (const float*)d_in[0];
    const float* slots    = (const float*)d_in[1];
    const float* horizons = (const float*)d_in[2];
    float* out = (float*)d_out;

    // 1024 blocks x 256 thr = 4096 waves; each wave: 4 fused tiles of 16 n.
    hipLaunchKernelGGL(attn_kernel, dim3(1024), dim3(256), 0, stream,
                       features, slots, horizons, out);
}